// Round 7
// baseline (549.860 us; speedup 1.0000x reference)
//
#include <hip/hip_runtime.h>

#define BLOCK 256
#define GRID_BLOCKS 2048   // 8192 waves = 256 CU x 32 waves/CU = full residency

typedef float v2f __attribute__((ext_vector_type(2)));

enum LId {FU1,FU2,KU1,KU2,HU1,HU2,MD1,MD2,MD3,HD1,HD2,KD1,KD2,HA1,HA2,KA1,KA2,FA1,FA2};

// dup-buffer layout: per layer, weights then bias, each element stored twice
// ({v,v}) so a uniform 8B load lands in an SGPR pair for v_pk_fma_f32.
__constant__ const int WN[19] = {4,4,16,16,36,36,176,256,96,24,16,8,4,32,4,24,4,16,4};
__constant__ const int BN[19] = {2,2, 4, 4, 6, 6, 16, 16, 6, 4, 4,2,2, 4,1, 4,1, 4,1};
__constant__ const int WOFF[19] = {0,6,12,32,52,94,136,328,600,702,730,750,760,766,802,807,835,840,860};
__constant__ const int BOFF[19] = {4,10,28,48,88,130,312,584,696,726,746,758,764,798,806,831,839,856,864};
// total 865 v2f = 1730 floats

struct PrepArgs {
    const float* w[19];
    const float* b[19];
};

__global__ __launch_bounds__(256) void prep_kernel(PrepArgs P, float* __restrict__ ws) {
    const int tid = blockIdx.x * 256 + threadIdx.x;
    for (int L = 0; L < 19; ++L) {
        const float* w = P.w[L];
        for (int e = tid; e < WN[L]; e += 1024) {
            float v = w[e];
            ws[2*(WOFF[L]+e)+0] = v;
            ws[2*(WOFF[L]+e)+1] = v;
        }
        const float* b = P.b[L];
        for (int e = tid; e < BN[L]; e += 1024) {
            float v = b[e];
            ws[2*(BOFF[L]+e)+0] = v;
            ws[2*(BOFF[L]+e)+1] = v;
        }
    }
}

// One row-pair per call. Weight pair is a wave-uniform 8B load -> SGPR pair ->
// single v_pk_fma_f32 per weight (2 rows). 4 cyc/inst but 2 FLOP/lane/cyc:
// this is the 157 TF fp32 path (scalar fma measured at half this rate).
template<int DIN,int DOUT,bool RELU>
__device__ __forceinline__ void lin(const v2f (&in)[DIN], v2f (&out)[DOUT],
                                    const v2f* __restrict__ w2, const v2f* __restrict__ b2) {
#pragma unroll
    for (int j = 0; j < DOUT; ++j) {
        v2f acc = b2[j];
#pragma unroll
        for (int i = 0; i < DIN; ++i)
            acc = __builtin_elementwise_fma(in[i], w2[i*DOUT + j], acc);
        if (RELU) {
            v2f z = {0.0f, 0.0f};
            out[j] = __builtin_elementwise_max(acc, z);
        } else {
            out[j] = acc;
        }
    }
}

__device__ __forceinline__ void do_pair(const float* __restrict__ x,
                                        float* __restrict__ out, int B,
                                        const v2f* __restrict__ dup,
                                        long long row0) {
    const bool full = (row0 + 2) <= B;

    // ---- load 2 rows x 11 features; transpose to per-feature pairs ----
    v2f xin[11];
    if (full) {
        const v2f* p = (const v2f*)(x + row0 * 11);  // 88B/pair, 8B aligned
        v2f v[11];
#pragma unroll
        for (int i = 0; i < 11; ++i) v[i] = p[i];
        const float* fv = (const float*)&v[0];
#pragma unroll
        for (int c = 0; c < 11; ++c) { xin[c].x = fv[c]; xin[c].y = fv[11 + c]; }
    } else {
        const float* pr = x + row0 * 11;
#pragma unroll
        for (int c = 0; c < 11; ++c) { xin[c].x = pr[c]; xin[c].y = pr[c]; }
    }

    // ---- f_up: [f, fd] -> 2 -> 2 ----
    v2f fin[2] = {xin[4], xin[10]};
    v2f tf[2], f_up[2];
    lin<2,2,true>(fin, tf, dup+WOFF[FU1], dup+BOFF[FU1]);
    lin<2,2,true>(tf, f_up, dup+WOFF[FU2], dup+BOFF[FU2]);

    // ---- k_up: [k, kd, f_up] -> 4 -> 4 ----
    v2f kin[4] = {xin[3], xin[9], f_up[0], f_up[1]};
    v2f tk[4], k_up[4];
    lin<4,4,true>(kin, tk, dup+WOFF[KU1], dup+BOFF[KU1]);
    lin<4,4,true>(tk, k_up, dup+WOFF[KU2], dup+BOFF[KU2]);

    // ---- h_up: [h, hd, k_up] -> 6 -> 6 ----
    v2f hin[6] = {xin[2], xin[8], k_up[0], k_up[1], k_up[2], k_up[3]};
    v2f th[6], h_up[6];
    lin<6,6,true>(hin, th, dup+WOFF[HU1], dup+BOFF[HU1]);
    lin<6,6,true>(th, h_up, dup+WOFF[HU2], dup+BOFF[HU2]);

    // ---- m_down: [m_obs(5), h_up(6)] -> 16 -> 16 -> 6 ----
    v2f min_[11] = {xin[0], xin[1], xin[5], xin[6], xin[7],
                    h_up[0], h_up[1], h_up[2], h_up[3], h_up[4], h_up[5]};
    v2f t16a[16], t16b[16], m_down[6];
    lin<11,16,true>(min_, t16a, dup+WOFF[MD1], dup+BOFF[MD1]);
    lin<16,16,true>(t16a, t16b, dup+WOFF[MD2], dup+BOFF[MD2]);
    lin<16,6,true>(t16b, m_down, dup+WOFF[MD3], dup+BOFF[MD3]);

    // ---- h_down: m_down -> 4 -> 4 ----
    v2f t4b[4], h_down[4];
    lin<6,4,true>(m_down, t4b, dup+WOFF[HD1], dup+BOFF[HD1]);
    lin<4,4,true>(t4b, h_down, dup+WOFF[HD2], dup+BOFF[HD2]);

    // ---- k_down: h_down -> 2 -> 2 ----
    v2f t2b[2], k_down[2];
    lin<4,2,true>(h_down, t2b, dup+WOFF[KD1], dup+BOFF[KD1]);
    lin<2,2,true>(t2b, k_down, dup+WOFF[KD2], dup+BOFF[KD2]);

    // ---- h_act: [h, hd, m_down(6)] -> 4 -> 1 (no relu on last) ----
    v2f ha_in[8] = {xin[2], xin[8], m_down[0], m_down[1], m_down[2], m_down[3], m_down[4], m_down[5]};
    v2f t4c[4], h_act[1];
    lin<8,4,true>(ha_in, t4c, dup+WOFF[HA1], dup+BOFF[HA1]);
    lin<4,1,false>(t4c, h_act, dup+WOFF[HA2], dup+BOFF[HA2]);

    // ---- k_act: [k, kd, h_down(4)] -> 4 -> 1 ----
    v2f ka_in[6] = {xin[3], xin[9], h_down[0], h_down[1], h_down[2], h_down[3]};
    v2f t4d[4], k_act[1];
    lin<6,4,true>(ka_in, t4d, dup+WOFF[KA1], dup+BOFF[KA1]);
    lin<4,1,false>(t4d, k_act, dup+WOFF[KA2], dup+BOFF[KA2]);

    // ---- f_act: [f, fd, k_down(2)] -> 4 -> 1 ----
    v2f fa_in[4] = {xin[4], xin[10], k_down[0], k_down[1]};
    v2f t4e[4], f_act[1];
    lin<4,4,true>(fa_in, t4e, dup+WOFF[FA1], dup+BOFF[FA1]);
    lin<4,1,false>(t4e, f_act, dup+WOFF[FA2], dup+BOFF[FA2]);

    // ---- store: per row [h_act, f_act, k_act] ----
    if (full) {
        float ob[6] = {h_act[0].x, f_act[0].x, k_act[0].x,
                       h_act[0].y, f_act[0].y, k_act[0].y};
        v2f* po = (v2f*)(out + row0 * 3);  // 24B/row, 8B aligned
#pragma unroll
        for (int i = 0; i < 3; ++i) po[i] = ((const v2f*)ob)[i];
    } else {
        out[row0*3+0] = h_act[0].x;
        out[row0*3+1] = f_act[0].x;
        out[row0*3+2] = k_act[0].x;
    }
}

__global__ __launch_bounds__(BLOCK) void pnet_kernel(
    const float* __restrict__ x, float* __restrict__ out, int B,
    const float* __restrict__ ws) {
    const v2f* dup = (const v2f*)ws;
    const long long npairs = ((long long)B + 1) / 2;
    const long long stride = (long long)gridDim.x * BLOCK;

    // grid-stride over row-pairs: waves stay resident, s_loads/I$ warm after
    // the first iteration, occupancy holds near-full through the kernel.
    for (long long p = (long long)blockIdx.x * BLOCK + threadIdx.x;
         p < npairs; p += stride) {
        do_pair(x, out, B, dup, p * 2);
    }
}

extern "C" void kernel_launch(void* const* d_in, const int* in_sizes, int n_in,
                              void* d_out, int out_size, void* d_ws, size_t ws_size,
                              hipStream_t stream) {
    const float* x = (const float*)d_in[0];
    float* out = (float*)d_out;
    const int B = in_sizes[0] / 11;

    PrepArgs P;
    for (int i = 0; i < 19; ++i) {
        P.w[i] = (const float*)d_in[1 + 2*i];
        P.b[i] = (const float*)d_in[2 + 2*i];
    }

    // duplicate weights/biases into d_ws as {v,v} pairs (1730 floats)
    prep_kernel<<<4, 256, 0, stream>>>(P, (float*)d_ws);

    const long long npairs = ((long long)B + 1) / 2;
    long long needed = (npairs + BLOCK - 1) / BLOCK;
    const int blocks = (int)(needed < GRID_BLOCKS ? needed : GRID_BLOCKS);
    pnet_kernel<<<blocks, BLOCK, 0, stream>>>(x, out, B, (const float*)d_ws);
}

// Round 8
// 279.486 us; speedup vs baseline: 1.9674x; 1.9674x over previous
//
#include <hip/hip_runtime.h>

#define BLOCK 256

typedef float v2f __attribute__((ext_vector_type(2)));

enum LId {FU1,FU2,KU1,KU2,HU1,HU2,MD1,MD2,MD3,HD1,HD2,KD1,KD2,HA1,HA2,KA1,KA2,FA1,FA2};

// dup-buffer layout: per layer, weights then bias, each element stored twice
// ({v,v}) so a uniform 8B load lands in an SGPR pair for v_pk_fma_f32.
__constant__ const int WN[19] = {4,4,16,16,36,36,176,256,96,24,16,8,4,32,4,24,4,16,4};
__constant__ const int BN[19] = {2,2, 4, 4, 6, 6, 16, 16, 6, 4, 4,2,2, 4,1, 4,1, 4,1};
__constant__ const int WOFF[19] = {0,6,12,32,52,94,136,328,600,702,730,750,760,766,802,807,835,840,860};
__constant__ const int BOFF[19] = {4,10,28,48,88,130,312,584,696,726,746,758,764,798,806,831,839,856,864};
// total 865 v2f = 1730 floats

struct PrepArgs {
    const float* w[19];
    const float* b[19];
};

__global__ __launch_bounds__(256) void prep_kernel(PrepArgs P, float* __restrict__ ws) {
    const int tid = blockIdx.x * 256 + threadIdx.x;
    for (int L = 0; L < 19; ++L) {
        const float* w = P.w[L];
        for (int e = tid; e < WN[L]; e += 1024) {
            float v = w[e];
            ws[2*(WOFF[L]+e)+0] = v;
            ws[2*(WOFF[L]+e)+1] = v;
        }
        const float* b = P.b[L];
        for (int e = tid; e < BN[L]; e += 1024) {
            float v = b[e];
            ws[2*(BOFF[L]+e)+0] = v;
            ws[2*(BOFF[L]+e)+1] = v;
        }
    }
}

// Two independent row-pairs (A=rows0,1  B=rows2,3) in lockstep: each s_loaded
// SGPR weight-pair feeds two v_pk_fma_f32 (4 rows per SMEM fetch -> halves the
// per-CU scalar-pipe occupancy vs R4), and the two chains give 2x ILP.
// STRAIGHT-LINE ONLY: wrapping this body in a loop (R7) breaks VOP3P codegen.
template<int DIN,int DOUT,bool RELU>
__device__ __forceinline__ void lin2(const v2f (&inA)[DIN], const v2f (&inB)[DIN],
                                     v2f (&outA)[DOUT], v2f (&outB)[DOUT],
                                     const v2f* __restrict__ w2, const v2f* __restrict__ b2) {
#pragma unroll
    for (int j = 0; j < DOUT; ++j) {
        v2f accA = b2[j];
        v2f accB = accA;
#pragma unroll
        for (int i = 0; i < DIN; ++i) {
            const v2f wv = w2[i*DOUT + j];
            accA = __builtin_elementwise_fma(inA[i], wv, accA);
            accB = __builtin_elementwise_fma(inB[i], wv, accB);
        }
        if (RELU) {
            v2f z = {0.0f, 0.0f};
            outA[j] = __builtin_elementwise_max(accA, z);
            outB[j] = __builtin_elementwise_max(accB, z);
        } else {
            outA[j] = accA;
            outB[j] = accB;
        }
    }
}

// amdgpu_waves_per_eu(4,4): HARD 4 waves/SIMD -> 128-VGPR budget. R6 showed
// __launch_bounds__(256,4) alone leaves the allocator at 64 VGPRs + scratch
// spills (WRITE_SIZE 23->159 MB); this attribute removes the incentive.
__global__ __attribute__((amdgpu_flat_work_group_size(256,256), amdgpu_waves_per_eu(4,4)))
void pnet_kernel(const float* __restrict__ x, float* __restrict__ out, int B,
                 const float* __restrict__ ws) {
    const long long t = (long long)blockIdx.x * BLOCK + threadIdx.x;
    const long long row0 = t * 4;
    if (row0 >= B) return;
    const bool full = (row0 + 4) <= B;

    const v2f* dup = (const v2f*)ws;

    // ---- load 4 rows x 11 features; transpose to per-feature v2f pairs ----
    v2f xa[11], xb[11];
    if (full) {
        const float4* p = (const float4*)(x + row0 * 11);  // 176*t bytes, 16B aligned
        float4 v[11];
#pragma unroll
        for (int i = 0; i < 11; ++i) v[i] = p[i];
        const float* fv = (const float*)&v[0];
#pragma unroll
        for (int c = 0; c < 11; ++c) {
            xa[c].x = fv[c];      xa[c].y = fv[11 + c];
            xb[c].x = fv[22 + c]; xb[c].y = fv[33 + c];
        }
    } else {
#pragma unroll
        for (int c = 0; c < 11; ++c) {
            long long r0 = row0 + 0 < B ? row0 + 0 : B - 1;
            long long r1 = row0 + 1 < B ? row0 + 1 : B - 1;
            long long r2 = row0 + 2 < B ? row0 + 2 : B - 1;
            long long r3 = row0 + 3 < B ? row0 + 3 : B - 1;
            xa[c].x = x[r0*11 + c]; xa[c].y = x[r1*11 + c];
            xb[c].x = x[r2*11 + c]; xb[c].y = x[r3*11 + c];
        }
    }

    // ---- f_up: [f, fd] -> 2 -> 2 ----
    v2f finA[2] = {xa[4], xa[10]}, finB[2] = {xb[4], xb[10]};
    v2f tfA[2], tfB[2], f_upA[2], f_upB[2];
    lin2<2,2,true>(finA, finB, tfA, tfB, dup+WOFF[FU1], dup+BOFF[FU1]);
    lin2<2,2,true>(tfA, tfB, f_upA, f_upB, dup+WOFF[FU2], dup+BOFF[FU2]);

    // ---- k_up: [k, kd, f_up] -> 4 -> 4 ----
    v2f kinA[4] = {xa[3], xa[9], f_upA[0], f_upA[1]};
    v2f kinB[4] = {xb[3], xb[9], f_upB[0], f_upB[1]};
    v2f tkA[4], tkB[4], k_upA[4], k_upB[4];
    lin2<4,4,true>(kinA, kinB, tkA, tkB, dup+WOFF[KU1], dup+BOFF[KU1]);
    lin2<4,4,true>(tkA, tkB, k_upA, k_upB, dup+WOFF[KU2], dup+BOFF[KU2]);

    // ---- h_up: [h, hd, k_up] -> 6 -> 6 ----
    v2f hinA[6] = {xa[2], xa[8], k_upA[0], k_upA[1], k_upA[2], k_upA[3]};
    v2f hinB[6] = {xb[2], xb[8], k_upB[0], k_upB[1], k_upB[2], k_upB[3]};
    v2f thA[6], thB[6], h_upA[6], h_upB[6];
    lin2<6,6,true>(hinA, hinB, thA, thB, dup+WOFF[HU1], dup+BOFF[HU1]);
    lin2<6,6,true>(thA, thB, h_upA, h_upB, dup+WOFF[HU2], dup+BOFF[HU2]);

    // ---- m_down: [m_obs(5), h_up(6)] -> 16 -> 16 -> 6 ----
    v2f minA[11] = {xa[0], xa[1], xa[5], xa[6], xa[7],
                    h_upA[0], h_upA[1], h_upA[2], h_upA[3], h_upA[4], h_upA[5]};
    v2f minB[11] = {xb[0], xb[1], xb[5], xb[6], xb[7],
                    h_upB[0], h_upB[1], h_upB[2], h_upB[3], h_upB[4], h_upB[5]};
    v2f t16aA[16], t16aB[16], t16bA[16], t16bB[16], m_downA[6], m_downB[6];
    lin2<11,16,true>(minA, minB, t16aA, t16aB, dup+WOFF[MD1], dup+BOFF[MD1]);
    lin2<16,16,true>(t16aA, t16aB, t16bA, t16bB, dup+WOFF[MD2], dup+BOFF[MD2]);
    lin2<16,6,true>(t16bA, t16bB, m_downA, m_downB, dup+WOFF[MD3], dup+BOFF[MD3]);

    // ---- h_down: m_down -> 4 -> 4 ----
    v2f t4bA[4], t4bB[4], h_downA[4], h_downB[4];
    lin2<6,4,true>(m_downA, m_downB, t4bA, t4bB, dup+WOFF[HD1], dup+BOFF[HD1]);
    lin2<4,4,true>(t4bA, t4bB, h_downA, h_downB, dup+WOFF[HD2], dup+BOFF[HD2]);

    // ---- k_down: h_down -> 2 -> 2 ----
    v2f t2bA[2], t2bB[2], k_downA[2], k_downB[2];
    lin2<4,2,true>(h_downA, h_downB, t2bA, t2bB, dup+WOFF[KD1], dup+BOFF[KD1]);
    lin2<2,2,true>(t2bA, t2bB, k_downA, k_downB, dup+WOFF[KD2], dup+BOFF[KD2]);

    // ---- h_act: [h, hd, m_down(6)] -> 4 -> 1 ----
    v2f haA[8] = {xa[2], xa[8], m_downA[0], m_downA[1], m_downA[2], m_downA[3], m_downA[4], m_downA[5]};
    v2f haB[8] = {xb[2], xb[8], m_downB[0], m_downB[1], m_downB[2], m_downB[3], m_downB[4], m_downB[5]};
    v2f t4cA[4], t4cB[4], h_actA[1], h_actB[1];
    lin2<8,4,true>(haA, haB, t4cA, t4cB, dup+WOFF[HA1], dup+BOFF[HA1]);
    lin2<4,1,false>(t4cA, t4cB, h_actA, h_actB, dup+WOFF[HA2], dup+BOFF[HA2]);

    // ---- k_act: [k, kd, h_down(4)] -> 4 -> 1 ----
    v2f kaA[6] = {xa[3], xa[9], h_downA[0], h_downA[1], h_downA[2], h_downA[3]};
    v2f kaB[6] = {xb[3], xb[9], h_downB[0], h_downB[1], h_downB[2], h_downB[3]};
    v2f t4dA[4], t4dB[4], k_actA[1], k_actB[1];
    lin2<6,4,true>(kaA, kaB, t4dA, t4dB, dup+WOFF[KA1], dup+BOFF[KA1]);
    lin2<4,1,false>(t4dA, t4dB, k_actA, k_actB, dup+WOFF[KA2], dup+BOFF[KA2]);

    // ---- f_act: [f, fd, k_down(2)] -> 4 -> 1 ----
    v2f faA[4] = {xa[4], xa[10], k_downA[0], k_downA[1]};
    v2f faB[4] = {xb[4], xb[10], k_downB[0], k_downB[1]};
    v2f t4eA[4], t4eB[4], f_actA[1], f_actB[1];
    lin2<4,4,true>(faA, faB, t4eA, t4eB, dup+WOFF[FA1], dup+BOFF[FA1]);
    lin2<4,1,false>(t4eA, t4eB, f_actA, f_actB, dup+WOFF[FA2], dup+BOFF[FA2]);

    // ---- store: per row [h_act, f_act, k_act] -> 12 floats = 3x float4 ----
    if (full) {
        float ob[12] = {h_actA[0].x, f_actA[0].x, k_actA[0].x,
                        h_actA[0].y, f_actA[0].y, k_actA[0].y,
                        h_actB[0].x, f_actB[0].x, k_actB[0].x,
                        h_actB[0].y, f_actB[0].y, k_actB[0].y};
        float4* po = (float4*)(out + row0 * 3);  // 48*t bytes, 16B aligned
#pragma unroll
        for (int i = 0; i < 3; ++i) po[i] = ((const float4*)ob)[i];
    } else {
        float hv[4] = {h_actA[0].x, h_actA[0].y, h_actB[0].x, h_actB[0].y};
        float fv2[4] = {f_actA[0].x, f_actA[0].y, f_actB[0].x, f_actB[0].y};
        float kv[4] = {k_actA[0].x, k_actA[0].y, k_actB[0].x, k_actB[0].y};
#pragma unroll
        for (int r = 0; r < 4; ++r) {
            long long row = row0 + r;
            if (row < B) {
                out[row*3+0] = hv[r];
                out[row*3+1] = fv2[r];
                out[row*3+2] = kv[r];
            }
        }
    }
}

extern "C" void kernel_launch(void* const* d_in, const int* in_sizes, int n_in,
                              void* d_out, int out_size, void* d_ws, size_t ws_size,
                              hipStream_t stream) {
    const float* x = (const float*)d_in[0];
    float* out = (float*)d_out;
    const int B = in_sizes[0] / 11;

    PrepArgs P;
    for (int i = 0; i < 19; ++i) {
        P.w[i] = (const float*)d_in[1 + 2*i];
        P.b[i] = (const float*)d_in[2 + 2*i];
    }

    // duplicate weights/biases into d_ws as {v,v} pairs (1730 floats)
    prep_kernel<<<4, 256, 0, stream>>>(P, (float*)d_ws);

    const long long nthreads = ((long long)B + 3) / 4;
    const int blocks = (int)((nthreads + BLOCK - 1) / BLOCK);
    pnet_kernel<<<blocks, BLOCK, 0, stream>>>(x, out, B, (const float*)d_ws);
}

// Round 9
// 256.490 us; speedup vs baseline: 2.1438x; 1.0897x over previous
//
#include <hip/hip_runtime.h>

#define BLOCK 256

typedef float v2f __attribute__((ext_vector_type(2)));

enum LId {FU1,FU2,KU1,KU2,HU1,HU2,MD1,MD2,MD3,HD1,HD2,KD1,KD2,HA1,HA2,KA1,KA2,FA1,FA2};

// dup-buffer layout: per layer, weights then bias, each element stored twice
// ({v,v}) so an 8B load yields a ready-made pair for v_pk_fma_f32.
__constant__ const int WN[19] = {4,4,16,16,36,36,176,256,96,24,16,8,4,32,4,24,4,16,4};
__constant__ const int BN[19] = {2,2, 4, 4, 6, 6, 16, 16, 6, 4, 4,2,2, 4,1, 4,1, 4,1};
__constant__ const int WOFF[19] = {0,6,12,32,52,94,136,328,600,702,730,750,760,766,802,807,835,840,860};
__constant__ const int BOFF[19] = {4,10,28,48,88,130,312,584,696,726,746,758,764,798,806,831,839,856,864};
#define NDUP 865   // total v2f entries = 1730 floats = 6920 B

struct PrepArgs {
    const float* w[19];
    const float* b[19];
};

__global__ __launch_bounds__(256) void prep_kernel(PrepArgs P, float* __restrict__ ws) {
    const int tid = blockIdx.x * 256 + threadIdx.x;
    for (int L = 0; L < 19; ++L) {
        const float* w = P.w[L];
        for (int e = tid; e < WN[L]; e += 1024) {
            float v = w[e];
            ws[2*(WOFF[L]+e)+0] = v;
            ws[2*(WOFF[L]+e)+1] = v;
        }
        const float* b = P.b[L];
        for (int e = tid; e < BN[L]; e += 1024) {
            float v = b[e];
            ws[2*(BOFF[L]+e)+0] = v;
            ws[2*(BOFF[L]+e)+1] = v;
        }
    }
}

// Weights come from LDS (wave-uniform address -> broadcast, conflict-free).
// Unlike s_load (SMEM returns out-of-order => every batch needs a full
// lgkmcnt(0) drain), ds_read returns in-order => the compiler pipelines with
// fine-grained lgkmcnt(N), keeping weight loads in flight under the pk-FMAs.
// STRAIGHT-LINE ONLY: wrapping this body in a loop (R7) breaks VOP3P codegen.
template<int DIN,int DOUT,bool RELU>
__device__ __forceinline__ void lin(const v2f (&in)[DIN], v2f (&out)[DOUT],
                                    const v2f* w2, const v2f* b2) {
#pragma unroll
    for (int j = 0; j < DOUT; ++j) {
        v2f acc = b2[j];
#pragma unroll
        for (int i = 0; i < DIN; ++i)
            acc = __builtin_elementwise_fma(in[i], w2[i*DOUT + j], acc);
        if (RELU) {
            v2f z = {0.0f, 0.0f};
            out[j] = __builtin_elementwise_max(acc, z);
        } else {
            out[j] = acc;
        }
    }
}

__global__ __launch_bounds__(BLOCK, 4) void pnet_kernel(
    const float* __restrict__ x, float* __restrict__ out, int B,
    const float* __restrict__ ws) {
    __shared__ v2f wlds[NDUP];
    // stage dup weights (6920 B) into LDS, coalesced
    for (int e = threadIdx.x; e < NDUP; e += BLOCK)
        wlds[e] = ((const v2f*)ws)[e];
    __syncthreads();

    const long long t = (long long)blockIdx.x * BLOCK + threadIdx.x;
    const long long row0 = t * 2;
    if (row0 >= B) return;
    const bool full = (row0 + 2) <= B;

    const v2f* dup = wlds;

    // ---- load 2 rows x 11 features; transpose to per-feature pairs ----
    v2f xin[11];
    if (full) {
        const v2f* p = (const v2f*)(x + row0 * 11);  // 88*t bytes, 8B aligned
        v2f v[11];
#pragma unroll
        for (int i = 0; i < 11; ++i) v[i] = p[i];
        const float* fv = (const float*)&v[0];
#pragma unroll
        for (int c = 0; c < 11; ++c) { xin[c].x = fv[c]; xin[c].y = fv[11 + c]; }
    } else {
        const float* pr = x + row0 * 11;
#pragma unroll
        for (int c = 0; c < 11; ++c) { xin[c].x = pr[c]; xin[c].y = pr[c]; }
    }

    // ---- f_up: [f, fd] -> 2 -> 2 ----
    v2f fin[2] = {xin[4], xin[10]};
    v2f tf[2], f_up[2];
    lin<2,2,true>(fin, tf, dup+WOFF[FU1], dup+BOFF[FU1]);
    lin<2,2,true>(tf, f_up, dup+WOFF[FU2], dup+BOFF[FU2]);

    // ---- k_up: [k, kd, f_up] -> 4 -> 4 ----
    v2f kin[4] = {xin[3], xin[9], f_up[0], f_up[1]};
    v2f tk[4], k_up[4];
    lin<4,4,true>(kin, tk, dup+WOFF[KU1], dup+BOFF[KU1]);
    lin<4,4,true>(tk, k_up, dup+WOFF[KU2], dup+BOFF[KU2]);

    // ---- h_up: [h, hd, k_up] -> 6 -> 6 ----
    v2f hin[6] = {xin[2], xin[8], k_up[0], k_up[1], k_up[2], k_up[3]};
    v2f th[6], h_up[6];
    lin<6,6,true>(hin, th, dup+WOFF[HU1], dup+BOFF[HU1]);
    lin<6,6,true>(th, h_up, dup+WOFF[HU2], dup+BOFF[HU2]);

    // ---- m_down: [m_obs(5), h_up(6)] -> 16 -> 16 -> 6 ----
    v2f min_[11] = {xin[0], xin[1], xin[5], xin[6], xin[7],
                    h_up[0], h_up[1], h_up[2], h_up[3], h_up[4], h_up[5]};
    v2f t16a[16], t16b[16], m_down[6];
    lin<11,16,true>(min_, t16a, dup+WOFF[MD1], dup+BOFF[MD1]);
    lin<16,16,true>(t16a, t16b, dup+WOFF[MD2], dup+BOFF[MD2]);
    lin<16,6,true>(t16b, m_down, dup+WOFF[MD3], dup+BOFF[MD3]);

    // ---- h_down: m_down -> 4 -> 4 ----
    v2f t4b[4], h_down[4];
    lin<6,4,true>(m_down, t4b, dup+WOFF[HD1], dup+BOFF[HD1]);
    lin<4,4,true>(t4b, h_down, dup+WOFF[HD2], dup+BOFF[HD2]);

    // ---- k_down: h_down -> 2 -> 2 ----
    v2f t2b[2], k_down[2];
    lin<4,2,true>(h_down, t2b, dup+WOFF[KD1], dup+BOFF[KD1]);
    lin<2,2,true>(t2b, k_down, dup+WOFF[KD2], dup+BOFF[KD2]);

    // ---- h_act: [h, hd, m_down(6)] -> 4 -> 1 (no relu on last) ----
    v2f ha_in[8] = {xin[2], xin[8], m_down[0], m_down[1], m_down[2], m_down[3], m_down[4], m_down[5]};
    v2f t4c[4], h_act[1];
    lin<8,4,true>(ha_in, t4c, dup+WOFF[HA1], dup+BOFF[HA1]);
    lin<4,1,false>(t4c, h_act, dup+WOFF[HA2], dup+BOFF[HA2]);

    // ---- k_act: [k, kd, h_down(4)] -> 4 -> 1 ----
    v2f ka_in[6] = {xin[3], xin[9], h_down[0], h_down[1], h_down[2], h_down[3]};
    v2f t4d[4], k_act[1];
    lin<6,4,true>(ka_in, t4d, dup+WOFF[KA1], dup+BOFF[KA1]);
    lin<4,1,false>(t4d, k_act, dup+WOFF[KA2], dup+BOFF[KA2]);

    // ---- f_act: [f, fd, k_down(2)] -> 4 -> 1 ----
    v2f fa_in[4] = {xin[4], xin[10], k_down[0], k_down[1]};
    v2f t4e[4], f_act[1];
    lin<4,4,true>(fa_in, t4e, dup+WOFF[FA1], dup+BOFF[FA1]);
    lin<4,1,false>(t4e, f_act, dup+WOFF[FA2], dup+BOFF[FA2]);

    // ---- store: per row [h_act, f_act, k_act] ----
    if (full) {
        float ob[6] = {h_act[0].x, f_act[0].x, k_act[0].x,
                       h_act[0].y, f_act[0].y, k_act[0].y};
        v2f* po = (v2f*)(out + row0 * 3);  // 24B/row, 8B aligned
#pragma unroll
        for (int i = 0; i < 3; ++i) po[i] = ((const v2f*)ob)[i];
    } else {
        out[row0*3+0] = h_act[0].x;
        out[row0*3+1] = f_act[0].x;
        out[row0*3+2] = k_act[0].x;
    }
}

extern "C" void kernel_launch(void* const* d_in, const int* in_sizes, int n_in,
                              void* d_out, int out_size, void* d_ws, size_t ws_size,
                              hipStream_t stream) {
    const float* x = (const float*)d_in[0];
    float* out = (float*)d_out;
    const int B = in_sizes[0] / 11;

    PrepArgs P;
    for (int i = 0; i < 19; ++i) {
        P.w[i] = (const float*)d_in[1 + 2*i];
        P.b[i] = (const float*)d_in[2 + 2*i];
    }

    // duplicate weights/biases into d_ws as {v,v} pairs (1730 floats)
    prep_kernel<<<4, 256, 0, stream>>>(P, (float*)d_ws);

    const long long nthreads = ((long long)B + 1) / 2;
    const int blocks = (int)((nthreads + BLOCK - 1) / BLOCK);
    pnet_kernel<<<blocks, BLOCK, 0, stream>>>(x, out, B, (const float*)d_ws);
}